// Round 5
// baseline (1106.319 us; speedup 1.0000x reference)
//
#include <hip/hip_runtime.h>

#define BB 8
#define NN 2048
#define KNN 20
#define NPOS (BB*NN)          // 16384 points
#define NEDGE (NPOS*KNN)      // 327680 edge positions

typedef _Float16 f16x8 __attribute__((ext_vector_type(8)));
typedef __fp16 fp16x2 __attribute__((ext_vector_type(2)));
typedef float f32x4 __attribute__((ext_vector_type(4)));

union H16 { _Float16 h; unsigned short u; };
__device__ __forceinline__ unsigned short f2h(float f){ H16 x; x.h = (_Float16)f; return x.u; }
__device__ __forceinline__ float h2f(unsigned short u){ H16 x; x.u = u; return (float)x.h; }
__device__ __forceinline__ unsigned pkrtz(float a, float b){
  union { fp16x2 h; unsigned u; } c; c.h = __builtin_amdgcn_cvt_pkrtz(a, b); return c.u;
}

// ---------- 1. de-mean: xt layout [b][n][4] ----------
__global__ __launch_bounds__(256) void k_demean(const float* __restrict__ pts, float* __restrict__ xt){
  int b = blockIdx.x / 3, d = blockIdx.x % 3;
  const float* row = pts + (size_t)(b*3 + d)*NN;
  __shared__ float red[256];
  int t = threadIdx.x;
  float s = 0.f;
  for (int n = t; n < NN; n += 256) s += row[n];
  red[t] = s; __syncthreads();
  for (int w = 128; w > 0; w >>= 1){ if (t < w) red[t] += red[t+w]; __syncthreads(); }
  float mean = red[0] * (1.0f/NN);
  for (int n = t; n < NN; n += 256) xt[(size_t)(b*NN + n)*4 + d] = row[n] - mean;
}

// ---------- 2. knn: 512 blocks, 32 points/block, 8 threads/point ----------
__global__ __launch_bounds__(256) void k_knn(const float* __restrict__ xt, unsigned short* __restrict__ idxo){
  __shared__ float4 xl[NN];
  __shared__ float tv[KNN][256];
  __shared__ unsigned short ti[KNN][256];
  int b = blockIdx.x >> 6;
  int pbase = (blockIdx.x & 63) * 32;
  int t = threadIdx.x;
  const float4* xb = (const float4*)xt + (size_t)b*NN;
  for (int m = t; m < NN; m += 256){
    float4 v = xb[m];
    v.w = v.x*v.x + v.y*v.y + v.z*v.z;
    xl[m] = v;
  }
  __syncthreads();
  int pl = t >> 3, g = t & 7;
  int n = pbase + pl;
  float4 xn = xl[n];
  float sqn = xn.w;
  for (int j = 0; j < 20; ++j){
    int m = g + (j << 3);
    float4 xm = xl[m];
    float nd = 2.f*(xn.x*xm.x + xn.y*xm.y + xn.z*xm.z) - sqn - xm.w;
    tv[j][t] = nd; ti[j][t] = (unsigned short)m;
  }
  float curmin = tv[0][t]; int minslot = 0;
  #pragma unroll
  for (int j = 1; j < 20; ++j){ float v = tv[j][t]; if (v < curmin){ curmin = v; minslot = j; } }
  for (int j = 20; j < 256; ++j){
    int m = g + (j << 3);
    float4 xm = xl[m];
    float nd = 2.f*(xn.x*xm.x + xn.y*xm.y + xn.z*xm.z) - sqn - xm.w;
    if (nd > curmin){
      tv[minslot][t] = nd; ti[minslot][t] = (unsigned short)m;
      curmin = tv[0][t]; minslot = 0;
      #pragma unroll
      for (int u = 1; u < 20; ++u){ float vv = tv[u][t]; if (vv < curmin){ curmin = vv; minslot = u; } }
    }
  }
  __syncthreads();
  for (int s = 4; s; s >>= 1){
    if (g < s){
      int src = t + s;
      for (int jj = 0; jj < 20; ++jj){
        float v = tv[jj][src];
        if (v > curmin){
          unsigned short mi = ti[jj][src];
          tv[minslot][t] = v; ti[minslot][t] = mi;
          curmin = tv[0][t]; minslot = 0;
          #pragma unroll
          for (int u = 1; u < 20; ++u){ float vv = tv[u][t]; if (vv < curmin){ curmin = vv; minslot = u; } }
        }
      }
    }
    __syncthreads();
  }
  if (g == 0){
    unsigned short* op = idxo + (size_t)(b*NN + pbase + pl)*KNN;
    #pragma unroll
    for (int j = 0; j < 20; ++j) op[j] = ti[j][t];
  }
}

// ---------- 3. weight prep: f32 -> f16, packed [w2|w3|w4|w5] ----------
__global__ __launch_bounds__(256) void k_wprep(const float* __restrict__ W2, const float* __restrict__ W3,
    const float* __restrict__ W4, const float* __restrict__ W5, unsigned short* __restrict__ wh){
  int i = blockIdx.x*256 + threadIdx.x;
  float v;
  if (i < 4096) v = W2[i];
  else if (i < 12288) v = W3[i-4096];
  else if (i < 45056) v = W4[i-12288];
  else v = W5[i-45056];
  wh[i] = f2h(v);
}

// ---------- 4. conv1: gather (nbr xyz, ctr xyz) -> y1 = W1*h, raw f16 [NEDGE][64] ----------
__global__ __launch_bounds__(256) void k_conv1(const float* __restrict__ xt, const unsigned short* __restrict__ idx,
    const float* __restrict__ W1, unsigned short* __restrict__ y1){
  __shared__ float Wl[64*6];
  int t = threadIdx.x;
  for (int i = t; i < 384; i += 256) Wl[i] = W1[i];
  __syncthreads();
  int e = blockIdx.x*256 + t;
  int p = e / KNN;
  int b = p >> 11;
  int n = p & (NN-1);
  int nb = idx[e];
  const float4* xb = (const float4*)xt + (size_t)b*NN;
  float4 xnb = xb[nb], xcn = xb[n];
  unsigned short* yo = y1 + (size_t)e*64;
  #pragma unroll
  for (int o = 0; o < 64; o += 8){
    unsigned pk[4];
    #pragma unroll
    for (int q = 0; q < 4; ++q){
      const float* wa = &Wl[(o+2*q)*6];
      const float* wb = &Wl[(o+2*q+1)*6];
      float va = wa[0]*xnb.x + wa[1]*xnb.y + wa[2]*xnb.z + wa[3]*xcn.x + wa[4]*xcn.y + wa[5]*xcn.z;
      float vb = wb[0]*xnb.x + wb[1]*xnb.y + wb[2]*xnb.z + wb[3]*xcn.x + wb[4]*xcn.y + wb[5]*xcn.z;
      pk[q] = pkrtz(va, vb);
    }
    uint4 u; u.x = pk[0]; u.y = pk[1]; u.z = pk[2]; u.w = pk[3];
    *reinterpret_cast<uint4*>(yo + o) = u;
  }
}

// ---------- 5. stats for y1 (C=64 f16), 64-sharded ----------
__global__ __launch_bounds__(256) void k_stats1(const unsigned short* __restrict__ y, float* __restrict__ st){
  int t = threadIdx.x;
  int c = t & 63, ro = t >> 6;
  float s = 0.f, q = 0.f;
  for (int rb = blockIdx.x; rb < NEDGE/4; rb += gridDim.x){
    float v = h2f(y[(size_t)(rb*4 + ro)*64 + c]);
    s += v; q += v*v;
  }
  __shared__ float red[256];
  red[t] = s; __syncthreads();
  if (t < 64){ for (int g = 1; g < 4; ++g) s += red[t + g*64]; }
  __syncthreads(); red[t] = q; __syncthreads();
  if (t < 64){
    for (int g = 1; g < 4; ++g) q += red[t + g*64];
    int shard = blockIdx.x & 63;
    atomicAdd(&st[c*64 + shard], s);
    atomicAdd(&st[64*64 + c*64 + shard], q);
  }
}

// ---------- 6. finalize BN -> act[2c]=scale, act[2c+1]=shift ----------
__global__ void k_fin(const float* __restrict__ st, const float* __restrict__ gw, const float* __restrict__ bw,
                      float* __restrict__ act, int C, float inv_n){
  int c = threadIdx.x;
  if (c >= C) return;
  float s = 0.f, q = 0.f;
  for (int i = 0; i < 64; ++i){ s += st[c*64 + i]; q += st[(size_t)C*64 + c*64 + i]; }
  float mean = s*inv_n;
  float var = q*inv_n - mean*mean;
  float sc = gw[c] * rsqrtf(var + 1e-5f);
  act[2*c] = sc; act[2*c+1] = bw[c] - mean*sc;
}

// ---------- 7. layer-1 max pool (y1 -> xc[:,0:64]) ----------
__global__ __launch_bounds__(256) void k_max64(const unsigned short* __restrict__ y, const float* __restrict__ actp,
    unsigned short* __restrict__ xc, int xcoff){
  int gidx = blockIdx.x*256 + threadIdx.x;
  int q = gidx >> 5, cp = gidx & 31;
  int c = cp*2;
  float sc0 = actp[2*c],   sh0 = actp[2*c+1];
  float sc1 = actp[2*c+2], sh1 = actp[2*c+3];
  const unsigned* base = reinterpret_cast<const unsigned*>(y + (size_t)q*KNN*64 + c);
  float m0 = 0.f, m1 = 0.f;
  #pragma unroll
  for (int j = 0; j < KNN; ++j){
    unsigned v = base[(size_t)j*32];
    m0 = fmaxf(m0, sc0*h2f((unsigned short)(v & 0xffffu)) + sh0);
    m1 = fmaxf(m1, sc1*h2f((unsigned short)(v >> 16)) + sh1);
  }
  *reinterpret_cast<unsigned*>(xc + (size_t)q*512 + xcoff + c) = pkrtz(m0, m1);
}

// ---------- 8. MFMA conv with store (+ optional window pool): swapped operands ----------
// acc[m][n]: pos = p0+16m+r16 (cols), och = o0+16n+4g+r (rows).
// POOL: tasks window-aligned (p0 = tt*20); store rows 0..31 (overlap benign), stats/pool rows < 20.
template<int CIN, int COUT, bool ACT, bool POOL>
__global__ __launch_bounds__(256, 4) void k_cstore(
    const unsigned short* __restrict__ in, const unsigned short* __restrict__ Wh,
    const float* __restrict__ actp, unsigned short* __restrict__ out, size_t slabStride,
    float* __restrict__ stat, unsigned* __restrict__ pm, int Cpm, int NT){
  constexpr int NKC = CIN/32;
  __shared__ unsigned short Tw[4][32][68];
  int t = threadIdx.x, lane = t & 63, w = t >> 6;
  int g = lane >> 4, r16 = lane & 15;
  int o0 = blockIdx.y * 64;
  const f16x8 zf = (f16x8)(_Float16)0.f;
  f16x8 scl8[ACT ? NKC : 1], shf8[ACT ? NKC : 1];
  if constexpr (ACT){
    #pragma unroll
    for (int kc = 0; kc < NKC; ++kc){
      const float4* apv = reinterpret_cast<const float4*>(actp + 2*(kc*32 + g*8));
      float4 q0 = apv[0], q1 = apv[1], q2 = apv[2], q3 = apv[3];
      f16x8 s, h;
      s[0]=(_Float16)q0.x; h[0]=(_Float16)q0.y; s[1]=(_Float16)q0.z; h[1]=(_Float16)q0.w;
      s[2]=(_Float16)q1.x; h[2]=(_Float16)q1.y; s[3]=(_Float16)q1.z; h[3]=(_Float16)q1.w;
      s[4]=(_Float16)q2.x; h[4]=(_Float16)q2.y; s[5]=(_Float16)q2.z; h[5]=(_Float16)q2.w;
      s[6]=(_Float16)q3.x; h[6]=(_Float16)q3.y; s[7]=(_Float16)q3.z; h[7]=(_Float16)q3.w;
      scl8[kc] = s; shf8[kc] = h;
    }
  }
  float sA[4][4] = {}, qA[4][4] = {};
  int wid = blockIdx.x*4 + w;
  for (int tt = wid; tt < NT; tt += gridDim.x*4){
    int p0 = POOL ? tt*20 : tt*32;
    int ra = p0 + r16, rb = p0 + 16 + r16;
    if constexpr (POOL){ ra = min(ra, NEDGE-1); rb = min(rb, NEDGE-1); }
    f32x4 acc[2][4];
    #pragma unroll
    for (int m = 0; m < 2; ++m)
      #pragma unroll
      for (int n = 0; n < 4; ++n) acc[m][n] = 0.f;
    #pragma unroll 4
    for (int kc = 0; kc < NKC; ++kc){
      f16x8 a0 = *reinterpret_cast<const f16x8*>(in + (size_t)ra*CIN + kc*32 + g*8);
      f16x8 a1 = *reinterpret_cast<const f16x8*>(in + (size_t)rb*CIN + kc*32 + g*8);
      if constexpr (ACT){
        a0 = __builtin_elementwise_max(a0*scl8[kc] + shf8[kc], zf);
        a1 = __builtin_elementwise_max(a1*scl8[kc] + shf8[kc], zf);
      }
      #pragma unroll
      for (int n = 0; n < 4; ++n){
        f16x8 bv = *reinterpret_cast<const f16x8*>(Wh + (size_t)(o0 + 16*n + r16)*CIN + kc*32 + g*8);
        acc[0][n] = __builtin_amdgcn_mfma_f32_16x16x32_f16(bv, a0, acc[0][n], 0, 0, 0);
        acc[1][n] = __builtin_amdgcn_mfma_f32_16x16x32_f16(bv, a1, acc[1][n], 0, 0, 0);
      }
    }
    // stats from regs (POOL: m=1 rows valid only when r16 < 4)
    #pragma unroll
    for (int n = 0; n < 4; ++n)
      #pragma unroll
      for (int r = 0; r < 4; ++r){
        float v0 = acc[0][n][r];
        sA[n][r] += v0; qA[n][r] += v0*v0;
        if (!POOL || r16 < 4){
          float v1 = acc[1][n][r];
          sA[n][r] += v1; qA[n][r] += v1*v1;
        }
      }
    // pack f16, per-wave LDS transpose
    #pragma unroll
    for (int m = 0; m < 2; ++m)
      #pragma unroll
      for (int n = 0; n < 4; ++n){
        unsigned u0 = pkrtz(acc[m][n][0], acc[m][n][1]);
        unsigned u1 = pkrtz(acc[m][n][2], acc[m][n][3]);
        uint2 d; d.x = u0; d.y = u1;
        *reinterpret_cast<uint2*>(&Tw[w][16*m + r16][16*n + 4*g]) = d;
      }
    // coalesced row store
    int pos = lane >> 1, chh = (lane & 1) * 32;
    const unsigned short* rp = &Tw[w][pos][chh];
    uint2 d0 = *reinterpret_cast<const uint2*>(rp);
    uint2 d1 = *reinterpret_cast<const uint2*>(rp + 4);
    uint2 d2 = *reinterpret_cast<const uint2*>(rp + 8);
    uint2 d3 = *reinterpret_cast<const uint2*>(rp + 12);
    uint2 d4 = *reinterpret_cast<const uint2*>(rp + 16);
    uint2 d5 = *reinterpret_cast<const uint2*>(rp + 20);
    uint2 d6 = *reinterpret_cast<const uint2*>(rp + 24);
    uint2 d7 = *reinterpret_cast<const uint2*>(rp + 28);
    if (!POOL || (p0 + pos) < NEDGE){
      uint4* op = reinterpret_cast<uint4*>(out + blockIdx.y*slabStride + ((size_t)(p0 + pos))*64 + chh);
      op[0] = make_uint4(d0.x, d0.y, d1.x, d1.y);
      op[1] = make_uint4(d2.x, d2.y, d3.x, d3.y);
      op[2] = make_uint4(d4.x, d4.y, d5.x, d5.y);
      op[3] = make_uint4(d6.x, d6.y, d7.x, d7.y);
    }
    if constexpr (POOL){
      // raw min/max over this task's window (rows 0..19), lane = channel
      float mxv = -1e30f, mnv = 1e30f;
      #pragma unroll
      for (int p = 0; p < 20; ++p){
        float v = h2f(Tw[w][p][lane]);
        mxv = fmaxf(mxv, v); mnv = fminf(mnv, v);
      }
      pm[(size_t)tt*Cpm + blockIdx.y*64 + lane] = pkrtz(mnv, mxv);
    }
  }
  // end: cross-lane (r16) reduce + sharded atomics
  #pragma unroll
  for (int n = 0; n < 4; ++n)
    #pragma unroll
    for (int r = 0; r < 4; ++r){
      float s = sA[n][r], q = qA[n][r];
      #pragma unroll
      for (int d = 1; d < 16; d <<= 1){ s += __shfl_xor(s, d); q += __shfl_xor(q, d); }
      sA[n][r] = s; qA[n][r] = q;
    }
  if (r16 == 0){
    int shard = wid & 63;
    #pragma unroll
    for (int n = 0; n < 4; ++n)
      #pragma unroll
      for (int r = 0; r < 4; ++r){
        int ch = o0 + 16*n + 4*g + r;
        atomicAdd(&stat[(size_t)ch*64 + shard], sA[n][r]);
        atomicAdd(&stat[(size_t)(COUT + ch)*64 + shard], qA[n][r]);
      }
  }
}

// ---------- 9. conv4: window-aligned, original operand order, pure-register min/max pool ----------
// acc[m][n]: pos = p0+16m+4g+r, och = o0+16n+r16.
__global__ __launch_bounds__(256, 4) void k_conv4(
    const unsigned short* __restrict__ inA, const unsigned short* __restrict__ inB,
    const unsigned short* __restrict__ Wh, const float* __restrict__ actp,
    float* __restrict__ stat, unsigned* __restrict__ pm){
  int t = threadIdx.x, lane = t & 63, w = t >> 6;
  int g = lane >> 4, r16 = lane & 15;
  int o0 = blockIdx.y * 64;
  const f16x8 zf = (f16x8)(_Float16)0.f;
  f16x8 scl8[4], shf8[4];
  #pragma unroll
  for (int kc = 0; kc < 4; ++kc){
    const float4* apv = reinterpret_cast<const float4*>(actp + 2*(kc*32 + g*8));
    float4 q0 = apv[0], q1 = apv[1], q2 = apv[2], q3 = apv[3];
    f16x8 s, h;
    s[0]=(_Float16)q0.x; h[0]=(_Float16)q0.y; s[1]=(_Float16)q0.z; h[1]=(_Float16)q0.w;
    s[2]=(_Float16)q1.x; h[2]=(_Float16)q1.y; s[3]=(_Float16)q1.z; h[3]=(_Float16)q1.w;
    s[4]=(_Float16)q2.x; h[4]=(_Float16)q2.y; s[5]=(_Float16)q2.z; h[5]=(_Float16)q2.w;
    s[6]=(_Float16)q3.x; h[6]=(_Float16)q3.y; s[7]=(_Float16)q3.z; h[7]=(_Float16)q3.w;
    scl8[kc] = s; shf8[kc] = h;
  }
  float s4[4] = {}, q4[4] = {};
  int wid = blockIdx.x*4 + w;
  for (int q = wid; q < NPOS; q += gridDim.x*4){
    int p0 = q*20;
    int ra = min(p0 + r16, NEDGE-1), rb = min(p0 + 16 + r16, NEDGE-1);
    f32x4 acc[2][4];
    #pragma unroll
    for (int m = 0; m < 2; ++m)
      #pragma unroll
      for (int n = 0; n < 4; ++n) acc[m][n] = 0.f;
    #pragma unroll
    for (int kc = 0; kc < 4; ++kc){
      const unsigned short* ab = (kc < 2) ? inA : inB;
      int kl = kc & 1;
      f16x8 a0 = *reinterpret_cast<const f16x8*>(ab + (size_t)ra*64 + kl*32 + g*8);
      f16x8 a1 = *reinterpret_cast<const f16x8*>(ab + (size_t)rb*64 + kl*32 + g*8);
      a0 = __builtin_elementwise_max(a0*scl8[kc] + shf8[kc], zf);
      a1 = __builtin_elementwise_max(a1*scl8[kc] + shf8[kc], zf);
      #pragma unroll
      for (int n = 0; n < 4; ++n){
        f16x8 bv = *reinterpret_cast<const f16x8*>(Wh + (size_t)(o0 + 16*n + r16)*128 + kc*32 + g*8);
        acc[0][n] = __builtin_amdgcn_mfma_f32_16x16x32_f16(a0, bv, acc[0][n], 0, 0, 0);
        acc[1][n] = __builtin_amdgcn_mfma_f32_16x16x32_f16(a1, bv, acc[1][n], 0, 0, 0);
      }
    }
    // stats: pos = 16m+4g+r; window rows < 20 -> m=0 all, m=1 only g==0
    #pragma unroll
    for (int n = 0; n < 4; ++n){
      #pragma unroll
      for (int r = 0; r < 4; ++r){ float v = acc[0][n][r]; s4[n] += v; q4[n] += v*v; }
      if (g == 0){
        #pragma unroll
        for (int r = 0; r < 4; ++r){ float v = acc[1][n][r]; s4[n] += v; q4[n] += v*v; }
      }
    }
    // window min/max via cross-lane reduce over g
    float mxv[4], mnv[4];
    #pragma unroll
    for (int n = 0; n < 4; ++n){
      float mx = fmaxf(fmaxf(acc[0][n][0], acc[0][n][1]), fmaxf(acc[0][n][2], acc[0][n][3]));
      float mn = fminf(fminf(acc[0][n][0], acc[0][n][1]), fminf(acc[0][n][2], acc[0][n][3]));
      if (g == 0){
        mx = fmaxf(mx, fmaxf(fmaxf(acc[1][n][0], acc[1][n][1]), fmaxf(acc[1][n][2], acc[1][n][3])));
        mn = fminf(mn, fminf(fminf(acc[1][n][0], acc[1][n][1]), fminf(acc[1][n][2], acc[1][n][3])));
      }
      mxv[n] = mx; mnv[n] = mn;
    }
    #pragma unroll
    for (int n = 0; n < 4; ++n){
      mxv[n] = fmaxf(mxv[n], __shfl_xor(mxv[n], 16));
      mnv[n] = fminf(mnv[n], __shfl_xor(mnv[n], 16));
      mxv[n] = fmaxf(mxv[n], __shfl_xor(mxv[n], 32));
      mnv[n] = fminf(mnv[n], __shfl_xor(mnv[n], 32));
    }
    if (lane < 16){
      #pragma unroll
      for (int n = 0; n < 4; ++n)
        pm[(size_t)q*256 + o0 + 16*n + lane] = pkrtz(mnv[n], mxv[n]);
    }
  }
  // end stats: reduce over g, atomics
  #pragma unroll
  for (int n = 0; n < 4; ++n){
    s4[n] += __shfl_xor(s4[n], 16); q4[n] += __shfl_xor(q4[n], 16);
    s4[n] += __shfl_xor(s4[n], 32); q4[n] += __shfl_xor(q4[n], 32);
  }
  if (lane < 16){
    int shard = wid & 63;
    #pragma unroll
    for (int n = 0; n < 4; ++n){
      int ch = o0 + 16*n + lane;
      atomicAdd(&stat[(size_t)ch*64 + shard], s4[n]);
      atomicAdd(&stat[(size_t)(256 + ch)*64 + shard], q4[n]);
    }
  }
}

// ---------- 10. pool finalize: xc[q][coff+c] = relu(sc*raw+sh), raw = sc>=0 ? mx : mn ----------
template<int C>
__global__ __launch_bounds__(256) void k_poolfin(const unsigned* __restrict__ pm, const float* __restrict__ actp,
    unsigned short* __restrict__ xc, int coff){
  int gi = blockIdx.x*256 + threadIdx.x;
  int q = gi / C, c = gi % C;
  unsigned v = pm[gi];
  float mnv = h2f((unsigned short)(v & 0xffffu));
  float mxv = h2f((unsigned short)(v >> 16));
  float sc = actp[2*c], sh = actp[2*c+1];
  float raw = (sc >= 0.f) ? mxv : mnv;
  xc[(size_t)q*512 + coff + c] = f2h(fmaxf(0.f, sc*raw + sh));
}

// ---------- 11. final: bn5+relu on y5 slabs [8][NPOS][64] f16 -> out [b][512][n] f32 ----------
__global__ void k_out(const unsigned short* __restrict__ y5, const float* __restrict__ actp, float* __restrict__ out){
  __shared__ float tile[32][33];
  int b = blockIdx.z, n0 = blockIdx.x*32, c0 = blockIdx.y*32;
  int lx = threadIdx.x, ly = threadIdx.y;
  int slab = c0 >> 6, cin = (c0 & 63) + lx;
  float sc = actp[2*(c0+lx)], sh = actp[2*(c0+lx)+1];
  const unsigned short* yb = y5 + (size_t)slab*NPOS*64 + (size_t)(b*NN + n0)*64 + cin;
  for (int yy = ly; yy < 32; yy += 8)
    tile[yy][lx] = fmaxf(0.f, sc*h2f(yb[(size_t)yy*64]) + sh);
  __syncthreads();
  for (int yy = ly; yy < 32; yy += 8)
    out[((size_t)(b*512 + c0 + yy))*NN + n0 + lx] = tile[lx][yy];
}

// ---------- launch ----------
extern "C" void kernel_launch(void* const* d_in, const int* in_sizes, int n_in,
                              void* d_out, int out_size, void* d_ws, size_t ws_size,
                              hipStream_t stream){
  const float* pts = (const float*)d_in[0];
  const float* W1 = (const float*)d_in[1];
  const float* W2 = (const float*)d_in[2];
  const float* W3 = (const float*)d_in[3];
  const float* W4 = (const float*)d_in[4];
  const float* W5 = (const float*)d_in[5];
  const float* g1 = (const float*)d_in[6];  const float* b1 = (const float*)d_in[7];
  const float* g2 = (const float*)d_in[8];  const float* b2 = (const float*)d_in[9];
  const float* g3 = (const float*)d_in[10]; const float* b3 = (const float*)d_in[11];
  const float* g4 = (const float*)d_in[12]; const float* b4 = (const float*)d_in[13];
  const float* g5 = (const float*)d_in[14]; const float* b5 = (const float*)d_in[15];

  char* ws = (char*)d_ws;
  float*          xt    = (float*)(ws + 0);                      // 256 KB
  unsigned short* idxu  = (unsigned short*)(ws + 262144);        // 640 KB
  float*          stats = (float*)(ws + 917504);                 // 512 KB
  float*          acts  = (float*)(ws + 1441792);                // 8 KB
  unsigned short* wh    = (unsigned short*)(ws + 1449984);       // 600 KB f16 weights
  // R1 (40MiB): y1 -> y3a -> y5
  unsigned short* y1    = (unsigned short*)(ws + 2097152);
  unsigned short* y3a   = (unsigned short*)(ws + 2097152);
  unsigned short* y5    = (unsigned short*)(ws + 2097152);
  // R2 (40MiB): y2 -> pm4 (16MB)
  unsigned short* y2    = (unsigned short*)(ws + 44040192);
  unsigned*       pm4   = (unsigned*)(ws + 44040192);
  // R3 (40MiB): pm2 (4MB, dead before conv3) -> y3b
  unsigned*       pm2   = (unsigned*)(ws + 85983232);
  unsigned short* y3b   = (unsigned short*)(ws + 85983232);
  unsigned short* xc    = (unsigned short*)(ws + 127926272);     // 16 MB
  unsigned*       pm3   = (unsigned*)(ws + 144703488);           // 8 MB -> ends ~153 MB
  float* out = (float*)d_out;

  unsigned short* w2h = wh;
  unsigned short* w3h = wh + 4096;
  unsigned short* w4h = wh + 12288;
  unsigned short* w5h = wh + 45056;

  float* st1 = stats + 0,  *st2 = stats + 8192, *st3 = stats + 16384, *st4 = stats + 32768, *st5 = stats + 65536;
  float* ac1 = acts + 0,   *ac2 = acts + 128,   *ac3 = acts + 256,    *ac4 = acts + 512,    *ac5 = acts + 1024;
  const size_t y3stride = (size_t)(85983232 - 2097152) / 2;

  hipMemsetAsync(stats, 0, 524288, stream);
  k_wprep<<<1200, 256, 0, stream>>>(W2, W3, W4, W5, wh);
  k_demean<<<24, 256, 0, stream>>>(pts, xt);
  k_knn<<<512, 256, 0, stream>>>(xt, idxu);
  k_conv1<<<NEDGE/256, 256, 0, stream>>>(xt, idxu, W1, y1);
  k_stats1<<<256, 256, 0, stream>>>(y1, st1);
  k_fin<<<1, 64, 0, stream>>>(st1, g1, b1, ac1, 64, 1.f/NEDGE);
  k_max64<<<NPOS*32/256, 256, 0, stream>>>(y1, ac1, xc, 0);
  k_cstore<64,64,true,true><<<dim3(1024,1), 256, 0, stream>>>(
      y1, w2h, ac1, y2, 0, st2, pm2, 64, NEDGE/20);
  k_fin<<<1, 64, 0, stream>>>(st2, g2, b2, ac2, 64, 1.f/NEDGE);
  k_poolfin<64><<<NPOS*64/256, 256, 0, stream>>>(pm2, ac2, xc, 64);
  k_cstore<64,128,true,true><<<dim3(1024,2), 256, 0, stream>>>(
      y2, w3h, ac2, y3a, y3stride, st3, pm3, 128, NEDGE/20);
  k_fin<<<1, 128, 0, stream>>>(st3, g3, b3, ac3, 128, 1.f/NEDGE);
  k_poolfin<128><<<NPOS*128/256, 256, 0, stream>>>(pm3, ac3, xc, 128);
  k_conv4<<<dim3(1024,4), 256, 0, stream>>>(y3a, y3b, w4h, ac3, st4, pm4);
  k_fin<<<1, 256, 0, stream>>>(st4, g4, b4, ac4, 256, 1.f/NEDGE);
  k_poolfin<256><<<NPOS*256/256, 256, 0, stream>>>(pm4, ac4, xc, 256);
  k_cstore<512,512,false,false><<<dim3(128,8), 256, 0, stream>>>(
      xc, w5h, nullptr, y5, (size_t)NPOS*64, st5, nullptr, 0, NPOS/32);
  k_fin<<<1, 512, 0, stream>>>(st5, g5, b5, ac5, 512, 1.f/NPOS);
  k_out<<<dim3(NN/32, 16, BB), dim3(32, 8), 0, stream>>>(y5, ac5, out);
}

// Round 6
// 982.414 us; speedup vs baseline: 1.1261x; 1.1261x over previous
//
#include <hip/hip_runtime.h>

#define BB 8
#define NN 2048
#define KNN 20
#define NPOS (BB*NN)          // 16384 points
#define NEDGE (NPOS*KNN)      // 327680 edge positions

typedef _Float16 f16x8 __attribute__((ext_vector_type(8)));
typedef __fp16 fp16x2 __attribute__((ext_vector_type(2)));
typedef float f32x4 __attribute__((ext_vector_type(4)));

union H16 { _Float16 h; unsigned short u; };
__device__ __forceinline__ unsigned short f2h(float f){ H16 x; x.h = (_Float16)f; return x.u; }
__device__ __forceinline__ float h2f(unsigned short u){ H16 x; x.u = u; return (float)x.h; }
__device__ __forceinline__ unsigned pkrtz(float a, float b){
  union { fp16x2 h; unsigned u; } c; c.h = __builtin_amdgcn_cvt_pkrtz(a, b); return c.u;
}

// ---------- 1. de-mean: xt layout [b][n][4] ----------
__global__ __launch_bounds__(256) void k_demean(const float* __restrict__ pts, float* __restrict__ xt){
  int b = blockIdx.x / 3, d = blockIdx.x % 3;
  const float* row = pts + (size_t)(b*3 + d)*NN;
  __shared__ float red[256];
  int t = threadIdx.x;
  float s = 0.f;
  for (int n = t; n < NN; n += 256) s += row[n];
  red[t] = s; __syncthreads();
  for (int w = 128; w > 0; w >>= 1){ if (t < w) red[t] += red[t+w]; __syncthreads(); }
  float mean = red[0] * (1.0f/NN);
  for (int n = t; n < NN; n += 256) xt[(size_t)(b*NN + n)*4 + d] = row[n] - mean;
}

// ---------- 2. knn: 512 blocks, 32 points/block, 8 threads/point ----------
__global__ __launch_bounds__(256) void k_knn(const float* __restrict__ xt, unsigned short* __restrict__ idxo){
  __shared__ float4 xl[NN];
  __shared__ float tv[KNN][256];
  __shared__ unsigned short ti[KNN][256];
  int b = blockIdx.x >> 6;
  int pbase = (blockIdx.x & 63) * 32;
  int t = threadIdx.x;
  const float4* xb = (const float4*)xt + (size_t)b*NN;
  for (int m = t; m < NN; m += 256){
    float4 v = xb[m];
    v.w = v.x*v.x + v.y*v.y + v.z*v.z;
    xl[m] = v;
  }
  __syncthreads();
  int pl = t >> 3, g = t & 7;
  int n = pbase + pl;
  float4 xn = xl[n];
  float sqn = xn.w;
  for (int j = 0; j < 20; ++j){
    int m = g + (j << 3);
    float4 xm = xl[m];
    float nd = 2.f*(xn.x*xm.x + xn.y*xm.y + xn.z*xm.z) - sqn - xm.w;
    tv[j][t] = nd; ti[j][t] = (unsigned short)m;
  }
  float curmin = tv[0][t]; int minslot = 0;
  #pragma unroll
  for (int j = 1; j < 20; ++j){ float v = tv[j][t]; if (v < curmin){ curmin = v; minslot = j; } }
  for (int j = 20; j < 256; ++j){
    int m = g + (j << 3);
    float4 xm = xl[m];
    float nd = 2.f*(xn.x*xm.x + xn.y*xm.y + xn.z*xm.z) - sqn - xm.w;
    if (nd > curmin){
      tv[minslot][t] = nd; ti[minslot][t] = (unsigned short)m;
      curmin = tv[0][t]; minslot = 0;
      #pragma unroll
      for (int u = 1; u < 20; ++u){ float vv = tv[u][t]; if (vv < curmin){ curmin = vv; minslot = u; } }
    }
  }
  __syncthreads();
  for (int s = 4; s; s >>= 1){
    if (g < s){
      int src = t + s;
      for (int jj = 0; jj < 20; ++jj){
        float v = tv[jj][src];
        if (v > curmin){
          unsigned short mi = ti[jj][src];
          tv[minslot][t] = v; ti[minslot][t] = mi;
          curmin = tv[0][t]; minslot = 0;
          #pragma unroll
          for (int u = 1; u < 20; ++u){ float vv = tv[u][t]; if (vv < curmin){ curmin = vv; minslot = u; } }
        }
      }
    }
    __syncthreads();
  }
  if (g == 0){
    unsigned short* op = idxo + (size_t)(b*NN + pbase + pl)*KNN;
    #pragma unroll
    for (int j = 0; j < 20; ++j) op[j] = ti[j][t];
  }
}

// ---------- 3. weight prep: f32 -> f16, packed [w2|w3|w4|w5] ----------
__global__ __launch_bounds__(256) void k_wprep(const float* __restrict__ W2, const float* __restrict__ W3,
    const float* __restrict__ W4, const float* __restrict__ W5, unsigned short* __restrict__ wh){
  int i = blockIdx.x*256 + threadIdx.x;
  float v;
  if (i < 4096) v = W2[i];
  else if (i < 12288) v = W3[i-4096];
  else if (i < 45056) v = W4[i-12288];
  else v = W5[i-45056];
  wh[i] = f2h(v);
}

// ---------- 4. conv1: gather (nbr xyz, ctr xyz) -> y1 = W1*h, raw f16 [NEDGE][64] ----------
__global__ __launch_bounds__(256) void k_conv1(const float* __restrict__ xt, const unsigned short* __restrict__ idx,
    const float* __restrict__ W1, unsigned short* __restrict__ y1){
  __shared__ float Wl[64*6];
  int t = threadIdx.x;
  for (int i = t; i < 384; i += 256) Wl[i] = W1[i];
  __syncthreads();
  int e = blockIdx.x*256 + t;
  int p = e / KNN;
  int b = p >> 11;
  int n = p & (NN-1);
  int nb = idx[e];
  const float4* xb = (const float4*)xt + (size_t)b*NN;
  float4 xnb = xb[nb], xcn = xb[n];
  unsigned short* yo = y1 + (size_t)e*64;
  #pragma unroll
  for (int o = 0; o < 64; o += 8){
    unsigned pk[4];
    #pragma unroll
    for (int q = 0; q < 4; ++q){
      const float* wa = &Wl[(o+2*q)*6];
      const float* wb = &Wl[(o+2*q+1)*6];
      float va = wa[0]*xnb.x + wa[1]*xnb.y + wa[2]*xnb.z + wa[3]*xcn.x + wa[4]*xcn.y + wa[5]*xcn.z;
      float vb = wb[0]*xnb.x + wb[1]*xnb.y + wb[2]*xnb.z + wb[3]*xcn.x + wb[4]*xcn.y + wb[5]*xcn.z;
      pk[q] = pkrtz(va, vb);
    }
    uint4 u; u.x = pk[0]; u.y = pk[1]; u.z = pk[2]; u.w = pk[3];
    *reinterpret_cast<uint4*>(yo + o) = u;
  }
}

// ---------- 5. stats for y1 (C=64 f16), 64-sharded ----------
__global__ __launch_bounds__(256) void k_stats1(const unsigned short* __restrict__ y, float* __restrict__ st){
  int t = threadIdx.x;
  int c = t & 63, ro = t >> 6;
  float s = 0.f, q = 0.f;
  for (int rb = blockIdx.x; rb < NEDGE/4; rb += gridDim.x){
    float v = h2f(y[(size_t)(rb*4 + ro)*64 + c]);
    s += v; q += v*v;
  }
  __shared__ float red[256];
  red[t] = s; __syncthreads();
  if (t < 64){ for (int g = 1; g < 4; ++g) s += red[t + g*64]; }
  __syncthreads(); red[t] = q; __syncthreads();
  if (t < 64){
    for (int g = 1; g < 4; ++g) q += red[t + g*64];
    int shard = blockIdx.x & 63;
    atomicAdd(&st[c*64 + shard], s);
    atomicAdd(&st[64*64 + c*64 + shard], q);
  }
}

// ---------- 6. finalize BN -> act f32 interleaved + actH f16 (scl[C] then shf[C]) ----------
__global__ void k_fin(const float* __restrict__ st, const float* __restrict__ gw, const float* __restrict__ bw,
                      float* __restrict__ act, unsigned short* __restrict__ actH, int C, float inv_n){
  int c = threadIdx.x;
  if (c >= C) return;
  float s = 0.f, q = 0.f;
  for (int i = 0; i < 64; ++i){ s += st[c*64 + i]; q += st[(size_t)C*64 + c*64 + i]; }
  float mean = s*inv_n;
  float var = q*inv_n - mean*mean;
  float sc = gw[c] * rsqrtf(var + 1e-5f);
  float sh = bw[c] - mean*sc;
  act[2*c] = sc; act[2*c+1] = sh;
  actH[c] = f2h(sc); actH[C + c] = f2h(sh);
}

// ---------- 7. layer-1 max pool (y1 -> xc[:,0:64]) ----------
__global__ __launch_bounds__(256) void k_max64(const unsigned short* __restrict__ y, const float* __restrict__ actp,
    unsigned short* __restrict__ xc, int xcoff){
  int gidx = blockIdx.x*256 + threadIdx.x;
  int q = gidx >> 5, cp = gidx & 31;
  int c = cp*2;
  float sc0 = actp[2*c],   sh0 = actp[2*c+1];
  float sc1 = actp[2*c+2], sh1 = actp[2*c+3];
  const unsigned* base = reinterpret_cast<const unsigned*>(y + (size_t)q*KNN*64 + c);
  float m0 = 0.f, m1 = 0.f;
  #pragma unroll
  for (int j = 0; j < KNN; ++j){
    unsigned v = base[(size_t)j*32];
    m0 = fmaxf(m0, sc0*h2f((unsigned short)(v & 0xffffu)) + sh0);
    m1 = fmaxf(m1, sc1*h2f((unsigned short)(v >> 16)) + sh1);
  }
  *reinterpret_cast<unsigned*>(xc + (size_t)q*512 + xcoff + c) = pkrtz(m0, m1);
}

// ---------- 8. MFMA conv with store (+ optional window pool): swapped operands ----------
// acc[m][n]: pos = p0+16m+r16 (cols), och = o0+16n+4g+r (rows).
template<int CIN, int COUT, bool ACT, bool POOL>
__global__ __launch_bounds__(256, 4) void k_cstore(
    const unsigned short* __restrict__ in, const unsigned short* __restrict__ Wh,
    const float* __restrict__ actp, unsigned short* __restrict__ out, size_t slabStride,
    float* __restrict__ stat, unsigned* __restrict__ pm, int Cpm, int NT){
  constexpr int NKC = CIN/32;
  __shared__ unsigned short Tw[4][32][68];
  int t = threadIdx.x, lane = t & 63, w = t >> 6;
  int g = lane >> 4, r16 = lane & 15;
  int o0 = blockIdx.y * 64;
  const f16x8 zf = (f16x8)(_Float16)0.f;
  f16x8 scl8[ACT ? NKC : 1], shf8[ACT ? NKC : 1];
  if constexpr (ACT){
    #pragma unroll
    for (int kc = 0; kc < NKC; ++kc){
      const float4* apv = reinterpret_cast<const float4*>(actp + 2*(kc*32 + g*8));
      float4 q0 = apv[0], q1 = apv[1], q2 = apv[2], q3 = apv[3];
      f16x8 s, h;
      s[0]=(_Float16)q0.x; h[0]=(_Float16)q0.y; s[1]=(_Float16)q0.z; h[1]=(_Float16)q0.w;
      s[2]=(_Float16)q1.x; h[2]=(_Float16)q1.y; s[3]=(_Float16)q1.z; h[3]=(_Float16)q1.w;
      s[4]=(_Float16)q2.x; h[4]=(_Float16)q2.y; s[5]=(_Float16)q2.z; h[5]=(_Float16)q2.w;
      s[6]=(_Float16)q3.x; h[6]=(_Float16)q3.y; s[7]=(_Float16)q3.z; h[7]=(_Float16)q3.w;
      scl8[kc] = s; shf8[kc] = h;
    }
  }
  float sA[4][4] = {}, qA[4][4] = {};
  int wid = blockIdx.x*4 + w;
  for (int tt = wid; tt < NT; tt += gridDim.x*4){
    int p0 = POOL ? tt*20 : tt*32;
    int ra = p0 + r16, rb = p0 + 16 + r16;
    if constexpr (POOL){ ra = min(ra, NEDGE-1); rb = min(rb, NEDGE-1); }
    f32x4 acc[2][4];
    #pragma unroll
    for (int m = 0; m < 2; ++m)
      #pragma unroll
      for (int n = 0; n < 4; ++n) acc[m][n] = 0.f;
    #pragma unroll 4
    for (int kc = 0; kc < NKC; ++kc){
      f16x8 a0 = *reinterpret_cast<const f16x8*>(in + (size_t)ra*CIN + kc*32 + g*8);
      f16x8 a1 = *reinterpret_cast<const f16x8*>(in + (size_t)rb*CIN + kc*32 + g*8);
      if constexpr (ACT){
        a0 = __builtin_elementwise_max(a0*scl8[kc] + shf8[kc], zf);
        a1 = __builtin_elementwise_max(a1*scl8[kc] + shf8[kc], zf);
      }
      #pragma unroll
      for (int n = 0; n < 4; ++n){
        f16x8 bv = *reinterpret_cast<const f16x8*>(Wh + (size_t)(o0 + 16*n + r16)*CIN + kc*32 + g*8);
        acc[0][n] = __builtin_amdgcn_mfma_f32_16x16x32_f16(bv, a0, acc[0][n], 0, 0, 0);
        acc[1][n] = __builtin_amdgcn_mfma_f32_16x16x32_f16(bv, a1, acc[1][n], 0, 0, 0);
      }
    }
    // stats from regs (POOL: m=1 rows valid only when r16 < 4)
    #pragma unroll
    for (int n = 0; n < 4; ++n)
      #pragma unroll
      for (int r = 0; r < 4; ++r){
        float v0 = acc[0][n][r];
        sA[n][r] += v0; qA[n][r] += v0*v0;
        if (!POOL || r16 < 4){
          float v1 = acc[1][n][r];
          sA[n][r] += v1; qA[n][r] += v1*v1;
        }
      }
    // pack f16, per-wave LDS transpose
    #pragma unroll
    for (int m = 0; m < 2; ++m)
      #pragma unroll
      for (int n = 0; n < 4; ++n){
        unsigned u0 = pkrtz(acc[m][n][0], acc[m][n][1]);
        unsigned u1 = pkrtz(acc[m][n][2], acc[m][n][3]);
        uint2 d; d.x = u0; d.y = u1;
        *reinterpret_cast<uint2*>(&Tw[w][16*m + r16][16*n + 4*g]) = d;
      }
    // coalesced row store
    int pos = lane >> 1, chh = (lane & 1) * 32;
    const unsigned short* rp = &Tw[w][pos][chh];
    uint2 d0 = *reinterpret_cast<const uint2*>(rp);
    uint2 d1 = *reinterpret_cast<const uint2*>(rp + 4);
    uint2 d2 = *reinterpret_cast<const uint2*>(rp + 8);
    uint2 d3 = *reinterpret_cast<const uint2*>(rp + 12);
    uint2 d4 = *reinterpret_cast<const uint2*>(rp + 16);
    uint2 d5 = *reinterpret_cast<const uint2*>(rp + 20);
    uint2 d6 = *reinterpret_cast<const uint2*>(rp + 24);
    uint2 d7 = *reinterpret_cast<const uint2*>(rp + 28);
    if (!POOL || (p0 + pos) < NEDGE){
      uint4* op = reinterpret_cast<uint4*>(out + blockIdx.y*slabStride + ((size_t)(p0 + pos))*64 + chh);
      op[0] = make_uint4(d0.x, d0.y, d1.x, d1.y);
      op[1] = make_uint4(d2.x, d2.y, d3.x, d3.y);
      op[2] = make_uint4(d4.x, d4.y, d5.x, d5.y);
      op[3] = make_uint4(d6.x, d6.y, d7.x, d7.y);
    }
    if constexpr (POOL){
      float mxv = -1e30f, mnv = 1e30f;
      #pragma unroll
      for (int p = 0; p < 20; ++p){
        float v = h2f(Tw[w][p][lane]);
        mxv = fmaxf(mxv, v); mnv = fminf(mnv, v);
      }
      pm[(size_t)tt*Cpm + blockIdx.y*64 + lane] = pkrtz(mnv, mxv);
    }
  }
  // end: cross-lane (r16) reduce + sharded atomics
  #pragma unroll
  for (int n = 0; n < 4; ++n)
    #pragma unroll
    for (int r = 0; r < 4; ++r){
      float s = sA[n][r], q = qA[n][r];
      #pragma unroll
      for (int d = 1; d < 16; d <<= 1){ s += __shfl_xor(s, d); q += __shfl_xor(q, d); }
      sA[n][r] = s; qA[n][r] = q;
    }
  if (r16 == 0){
    int shard = wid & 63;
    #pragma unroll
    for (int n = 0; n < 4; ++n)
      #pragma unroll
      for (int r = 0; r < 4; ++r){
        int ch = o0 + 16*n + 4*g + r;
        atomicAdd(&stat[(size_t)ch*64 + shard], sA[n][r]);
        atomicAdd(&stat[(size_t)(COUT + ch)*64 + shard], qA[n][r]);
      }
  }
}

// ---------- 9. conv4: single pass over A, all 4 o-slices per wave, reg-only pool ----------
// acc[m][n]: pos = p0+16m+4g+r, och = o*64+16n+r16. A loaded once (20 rows), BN folded at load.
__global__ __launch_bounds__(256, 3) void k_conv4(
    const unsigned short* __restrict__ inA, const unsigned short* __restrict__ inB,
    const unsigned short* __restrict__ Wh, const unsigned short* __restrict__ actH,
    float* __restrict__ stat, unsigned* __restrict__ pm){
  int t = threadIdx.x, lane = t & 63, w = t >> 6;
  int g = lane >> 4, r16 = lane & 15;
  const f16x8 zf = (f16x8)(_Float16)0.f;
  float sA[4][4] = {}, qA[4][4] = {};   // [o][n]
  int wid = blockIdx.x*4 + w;
  for (int q = wid; q < NPOS; q += 4096){
    int p0 = q*20;
    int ra = p0 + r16;
    int rb = p0 + 16 + (r16 < 3 ? r16 : 3);  // clamp to window rows 16..19
    f16x8 A0[4], A1[4];
    #pragma unroll
    for (int kc = 0; kc < 4; ++kc){
      const unsigned short* ab = (kc < 2) ? inA : inB;
      int co = (kc & 1)*32 + g*8;
      f16x8 scl = *reinterpret_cast<const f16x8*>(actH + kc*32 + g*8);
      f16x8 shf = *reinterpret_cast<const f16x8*>(actH + 128 + kc*32 + g*8);
      f16x8 a0 = *reinterpret_cast<const f16x8*>(ab + (size_t)ra*64 + co);
      f16x8 a1 = *reinterpret_cast<const f16x8*>(ab + (size_t)rb*64 + co);
      A0[kc] = __builtin_elementwise_max(a0*scl + shf, zf);
      A1[kc] = __builtin_elementwise_max(a1*scl + shf, zf);
    }
    #pragma unroll
    for (int o = 0; o < 4; ++o){
      f32x4 acc[2][4];
      #pragma unroll
      for (int m = 0; m < 2; ++m)
        #pragma unroll
        for (int n = 0; n < 4; ++n) acc[m][n] = 0.f;
      #pragma unroll
      for (int kc = 0; kc < 4; ++kc)
        #pragma unroll
        for (int n = 0; n < 4; ++n){
          f16x8 bv = *reinterpret_cast<const f16x8*>(Wh + (size_t)(o*64 + 16*n + r16)*128 + kc*32 + g*8);
          acc[0][n] = __builtin_amdgcn_mfma_f32_16x16x32_f16(A0[kc], bv, acc[0][n], 0, 0, 0);
          acc[1][n] = __builtin_amdgcn_mfma_f32_16x16x32_f16(A1[kc], bv, acc[1][n], 0, 0, 0);
        }
      #pragma unroll
      for (int n = 0; n < 4; ++n){
        float mx = -1e30f, mn = 1e30f;
        #pragma unroll
        for (int r = 0; r < 4; ++r){
          float v = acc[0][n][r];
          sA[o][n] += v; qA[o][n] += v*v;
          mx = fmaxf(mx, v); mn = fminf(mn, v);
        }
        if (g == 0){
          #pragma unroll
          for (int r = 0; r < 4; ++r){
            float v = acc[1][n][r];
            sA[o][n] += v; qA[o][n] += v*v;
            mx = fmaxf(mx, v); mn = fminf(mn, v);
          }
        }
        mx = fmaxf(mx, __shfl_xor(mx, 16)); mn = fminf(mn, __shfl_xor(mn, 16));
        mx = fmaxf(mx, __shfl_xor(mx, 32)); mn = fminf(mn, __shfl_xor(mn, 32));
        if (lane < 16)
          pm[(size_t)q*256 + o*64 + 16*n + lane] = pkrtz(mn, mx);
      }
    }
  }
  // end: reduce stats over g, sharded atomics
  int shard = wid & 63;
  #pragma unroll
  for (int o = 0; o < 4; ++o)
    #pragma unroll
    for (int n = 0; n < 4; ++n){
      float s = sA[o][n], qq = qA[o][n];
      s += __shfl_xor(s, 16); qq += __shfl_xor(qq, 16);
      s += __shfl_xor(s, 32); qq += __shfl_xor(qq, 32);
      if (lane < 16){
        int ch = o*64 + 16*n + r16;
        atomicAdd(&stat[(size_t)ch*64 + shard], s);
        atomicAdd(&stat[(size_t)(256 + ch)*64 + shard], qq);
      }
    }
}

// ---------- 10. pool finalize: xc[q][coff+c] = relu(sc*raw+sh), raw = sc>=0 ? mx : mn ----------
template<int C>
__global__ __launch_bounds__(256) void k_poolfin(const unsigned* __restrict__ pm, const float* __restrict__ actp,
    unsigned short* __restrict__ xc, int coff){
  int gi = blockIdx.x*256 + threadIdx.x;
  int q = gi / C, c = gi % C;
  unsigned v = pm[gi];
  float mnv = h2f((unsigned short)(v & 0xffffu));
  float mxv = h2f((unsigned short)(v >> 16));
  float sc = actp[2*c], sh = actp[2*c+1];
  float raw = (sc >= 0.f) ? mxv : mnv;
  xc[(size_t)q*512 + coff + c] = f2h(fmaxf(0.f, sc*raw + sh));
}

// ---------- 11. final: bn5+relu on y5 slabs [8][NPOS][64] f16 -> out [b][512][n] f32 ----------
__global__ void k_out(const unsigned short* __restrict__ y5, const float* __restrict__ actp, float* __restrict__ out){
  __shared__ float tile[32][33];
  int b = blockIdx.z, n0 = blockIdx.x*32, c0 = blockIdx.y*32;
  int lx = threadIdx.x, ly = threadIdx.y;
  int slab = c0 >> 6, cin = (c0 & 63) + lx;
  float sc = actp[2*(c0+lx)], sh = actp[2*(c0+lx)+1];
  const unsigned short* yb = y5 + (size_t)slab*NPOS*64 + (size_t)(b*NN + n0)*64 + cin;
  for (int yy = ly; yy < 32; yy += 8)
    tile[yy][lx] = fmaxf(0.f, sc*h2f(yb[(size_t)yy*64]) + sh);
  __syncthreads();
  for (int yy = ly; yy < 32; yy += 8)
    out[((size_t)(b*512 + c0 + yy))*NN + n0 + lx] = tile[lx][yy];
}

// ---------- launch ----------
extern "C" void kernel_launch(void* const* d_in, const int* in_sizes, int n_in,
                              void* d_out, int out_size, void* d_ws, size_t ws_size,
                              hipStream_t stream){
  const float* pts = (const float*)d_in[0];
  const float* W1 = (const float*)d_in[1];
  const float* W2 = (const float*)d_in[2];
  const float* W3 = (const float*)d_in[3];
  const float* W4 = (const float*)d_in[4];
  const float* W5 = (const float*)d_in[5];
  const float* g1 = (const float*)d_in[6];  const float* b1 = (const float*)d_in[7];
  const float* g2 = (const float*)d_in[8];  const float* b2 = (const float*)d_in[9];
  const float* g3 = (const float*)d_in[10]; const float* b3 = (const float*)d_in[11];
  const float* g4 = (const float*)d_in[12]; const float* b4 = (const float*)d_in[13];
  const float* g5 = (const float*)d_in[14]; const float* b5 = (const float*)d_in[15];

  char* ws = (char*)d_ws;
  float*          xt    = (float*)(ws + 0);                      // 256 KB
  unsigned short* idxu  = (unsigned short*)(ws + 262144);        // 640 KB
  float*          stats = (float*)(ws + 917504);                 // 512 KB
  float*          acts  = (float*)(ws + 1441792);                // 8 KB f32
  unsigned short* actsH = (unsigned short*)(ws + 1449984);       // 4 KB f16
  unsigned short* wh    = (unsigned short*)(ws + 1454080);       // 600 KB f16 weights
  // R1 (40MiB): y1 -> y3a -> y5
  unsigned short* y1    = (unsigned short*)(ws + 2097152);
  unsigned short* y3a   = (unsigned short*)(ws + 2097152);
  unsigned short* y5    = (unsigned short*)(ws + 2097152);
  // R2 (40MiB): y2 -> pm4 (16MB)
  unsigned short* y2    = (unsigned short*)(ws + 44040192);
  unsigned*       pm4   = (unsigned*)(ws + 44040192);
  // R3 (40MiB): pm2 (4MB, dead before conv3) -> y3b
  unsigned*       pm2   = (unsigned*)(ws + 85983232);
  unsigned short* y3b   = (unsigned short*)(ws + 85983232);
  unsigned short* xc    = (unsigned short*)(ws + 127926272);     // 16 MB
  unsigned*       pm3   = (unsigned*)(ws + 144703488);           // 8 MB -> ends ~153 MB
  float* out = (float*)d_out;

  unsigned short* w2h = wh;
  unsigned short* w3h = wh + 4096;
  unsigned short* w4h = wh + 12288;
  unsigned short* w5h = wh + 45056;

  float* st1 = stats + 0,  *st2 = stats + 8192, *st3 = stats + 16384, *st4 = stats + 32768, *st5 = stats + 65536;
  float* ac1 = acts + 0,   *ac2 = acts + 128,   *ac3 = acts + 256,    *ac4 = acts + 512,    *ac5 = acts + 1024;
  unsigned short* aH1 = actsH + 0,   *aH2 = actsH + 128, *aH3 = actsH + 256,
                * aH4 = actsH + 512, *aH5 = actsH + 1024;
  const size_t y3stride = (size_t)(85983232 - 2097152) / 2;

  hipMemsetAsync(stats, 0, 524288, stream);
  k_wprep<<<1200, 256, 0, stream>>>(W2, W3, W4, W5, wh);
  k_demean<<<24, 256, 0, stream>>>(pts, xt);
  k_knn<<<512, 256, 0, stream>>>(xt, idxu);
  k_conv1<<<NEDGE/256, 256, 0, stream>>>(xt, idxu, W1, y1);
  k_stats1<<<256, 256, 0, stream>>>(y1, st1);
  k_fin<<<1, 64, 0, stream>>>(st1, g1, b1, ac1, aH1, 64, 1.f/NEDGE);
  k_max64<<<NPOS*32/256, 256, 0, stream>>>(y1, ac1, xc, 0);
  k_cstore<64,64,true,true><<<dim3(1024,1), 256, 0, stream>>>(
      y1, w2h, ac1, y2, 0, st2, pm2, 64, NEDGE/20);
  k_fin<<<1, 64, 0, stream>>>(st2, g2, b2, ac2, aH2, 64, 1.f/NEDGE);
  k_poolfin<64><<<NPOS*64/256, 256, 0, stream>>>(pm2, ac2, xc, 64);
  k_cstore<64,128,true,true><<<dim3(1024,2), 256, 0, stream>>>(
      y2, w3h, ac2, y3a, y3stride, st3, pm3, 128, NEDGE/20);
  k_fin<<<1, 128, 0, stream>>>(st3, g3, b3, ac3, aH3, 128, 1.f/NEDGE);
  k_poolfin<128><<<NPOS*128/256, 256, 0, stream>>>(pm3, ac3, xc, 128);
  k_conv4<<<dim3(1024), 256, 0, stream>>>(y3a, y3b, w4h, aH3, st4, pm4);
  k_fin<<<1, 256, 0, stream>>>(st4, g4, b4, ac4, aH4, 256, 1.f/NEDGE);
  k_poolfin<256><<<NPOS*256/256, 256, 0, stream>>>(pm4, ac4, xc, 256);
  k_cstore<512,512,false,false><<<dim3(128,8), 256, 0, stream>>>(
      xc, w5h, nullptr, y5, (size_t)NPOS*64, st5, nullptr, 0, NPOS/32);
  k_fin<<<1, 512, 0, stream>>>(st5, g5, b5, ac5, aH5, 512, 1.f/NPOS);
  k_out<<<dim3(NN/32, 16, BB), dim3(32, 8), 0, stream>>>(y5, ac5, out);
}